// Round 10
// baseline (360.269 us; speedup 1.0000x reference)
//
#include <hip/hip_runtime.h>

#define B_ 256
#define T_ 128
#define D_ 768
#define K_ 74
#define C_ 128
#define TK_ 9472      // T_*K_
#define BT_ 32768     // B_*T_
#define EMS_ 18944    // B_*K_  (em time-slice stride)

#define WAVE_SYNC() asm volatile("s_waitcnt lgkmcnt(0)" ::: "memory")

// ---------------- K0: pad W1 -> W1q[4][768][20], W2 -> W2q[4][74][20]
__global__ void pad_weights(const float* __restrict__ W1, const float* __restrict__ W2,
                            float* __restrict__ W1q, float* __restrict__ W2q)
{
    int idx = blockIdx.x * 256 + threadIdx.x;
    if (idx < 4 * 768 * 20) {
        int nq = idx / (768 * 20); int rem = idx - nq * (768 * 20);
        int k = rem / 20, j = rem - k * 20;
        int c = nq * 19 + j;
        W1q[idx] = (j < 19 && c < 74) ? W1[k * 74 + c] : 0.f;
    }
    if (idx < 4 * 74 * 20) {
        int nq = idx / (74 * 20); int rem = idx - nq * (74 * 20);
        int k = rem / 20, j = rem - k * 20;
        int c = nq * 19 + j;
        W2q[idx] = (j < 19 && c < 74) ? W2[k * 74 + c] : 0.f;
    }
}

// ---------------- K1a: logits partials, K-split x2. ks=0 -> outA(logits), ks=1 -> outB(y scratch)
__global__ __launch_bounds__(256) void gemm_logits_part(const float* __restrict__ feats,
    const float* __restrict__ W1q, float* __restrict__ outA, float* __restrict__ outB)
{
    int orig = blockIdx.x;                    // grid 1024, divisible by 8
    int vb = (orig & 7) * 128 + (orig >> 3);  // contiguous chunk per XCD
    int rb = vb >> 3, nq = (vb >> 1) & 3, ks = vb & 1;
    int tid = threadIdx.x;
    int r = rb * 256 + tid;
    int c0 = nq * 19;
    const float* frow = feats + (size_t)r * 768 + ks * 384;
    const float* wq = W1q + nq * (768 * 20) + ks * 384 * 20;
    float acc[20];
    #pragma unroll
    for (int j = 0; j < 20; ++j) acc[j] = 0.f;

    for (int k0 = 0; k0 < 384; k0 += 16) {
        float4 a[4];
        #pragma unroll
        for (int q = 0; q < 4; ++q) a[q] = *(const float4*)(frow + k0 + 4 * q);
        #pragma unroll
        for (int u = 0; u < 16; ++u) {
            float av = ((const float*)a)[u];
            const float* wr = wq + (k0 + u) * 20;
            #pragma unroll
            for (int j = 0; j < 20; ++j) acc[j] += av * wr[j];
        }
    }
    float* P = ks ? outB : outA;
    #pragma unroll
    for (int j = 0; j < 19; ++j) {
        int c = c0 + j;
        if (c < 74) P[(size_t)r * 74 + c] = acc[j];
    }
}

// ---------------- K1b: logits = A + B + b1
__global__ void logits_sum(const float* __restrict__ Bp, const float* __restrict__ b1,
                           float* __restrict__ logits)
{
    int idx = blockIdx.x * 256 + threadIdx.x;
    int r = idx / 74; int c = idx - r * 74;
    logits[idx] = logits[idx] + Bp[idx] + b1[c];
}

// ---------------- K2: sim partials
__global__ __launch_bounds__(256) void sim_partial(const float* __restrict__ logits,
    const float* __restrict__ cache, float* __restrict__ part)
{
    __shared__ float As[74][68];
    __shared__ float Bs[74][68];
    int tid = threadIdx.x;
    int tx = tid & 15, ty = tid >> 4;
    int bid = blockIdx.x;
    int jc = bid >> 3;
    int mt = (bid >> 1) & 3;
    int nt = bid & 1;
    int p0 = mt * 64, q0 = nt * 64;
    float acc[4][4] = {};
    for (int jj = 0; jj < 4; ++jj) {
        int j = jc * 4 + jj;
        for (int it = 0; it < 19; ++it) {
            int lin = it * 256 + tid;
            if (lin < 64 * 74) {
                int r = lin / 74, ik = lin - r * 74;
                As[ik][r] = logits[(p0 + r) * TK_ + j * 74 + ik];
                Bs[ik][r] = cache[(q0 + r) * TK_ + j * 74 + ik];
            }
        }
        __syncthreads();
        for (int ik = 0; ik < 74; ++ik) {
            float4 a = *(const float4*)&As[ik][4 * tx];
            float4 b = *(const float4*)&Bs[ik][4 * ty];
            const float* ap = (const float*)&a;
            const float* bp = (const float*)&b;
            #pragma unroll
            for (int i = 0; i < 4; ++i)
                #pragma unroll
                for (int q = 0; q < 4; ++q) acc[i][q] += ap[i] * bp[q];
        }
        __syncthreads();
    }
    #pragma unroll
    for (int i = 0; i < 4; ++i)
        #pragma unroll
        for (int q = 0; q < 4; ++q)
            part[jc * (B_ * C_) + (p0 + 4 * tx + i) * C_ + q0 + 4 * ty + q] = acc[i][q];
}

__global__ void sim_reduce(const float* __restrict__ part, float* __restrict__ sim)
{
    int idx = blockIdx.x * 256 + threadIdx.x;
    float s = 0.f;
    for (int jc = 0; jc < 32; ++jc) s += part[jc * (B_ * C_) + idx];
    sim[idx] = s;
}

__global__ void softmax128(const float* __restrict__ sim, float* __restrict__ p)
{
    __shared__ float red[128];
    int q = threadIdx.x, row = blockIdx.x;
    float v = sim[row * 128 + q];
    red[q] = v; __syncthreads();
    for (int s = 64; s > 0; s >>= 1) { if (q < s) red[q] = fmaxf(red[q], red[q + s]); __syncthreads(); }
    float m = red[0]; __syncthreads();
    float e = expf(v - m);
    red[q] = e; __syncthreads();
    for (int s = 64; s > 0; s >>= 1) { if (q < s) red[q] += red[q + s]; __syncthreads(); }
    float sum = red[0];
    p[row * 128 + q] = e / sum;
}

// ---------------- K4a: y = logits + 0.5*(p @ c_r)
__global__ __launch_bounds__(256) void gemm_h_y(const float* __restrict__ pmat,
    const float* __restrict__ cache, const float* __restrict__ logits, float* __restrict__ y)
{
    __shared__ float As[128][68];
    __shared__ float Bs[128][68];
    int tid = threadIdx.x;
    int tx = tid & 15, ty = tid >> 4;
    int mt = blockIdx.x / 148, nt = blockIdx.x - mt * 148;
    int r0 = mt * 64, n0 = nt * 64;
    #pragma unroll
    for (int it = 0; it < 32; ++it) {
        int lin = it * 256 + tid;
        int r = lin >> 7, kk = lin & 127;
        As[kk][r] = pmat[(r0 + r) * 128 + kk];
    }
    #pragma unroll
    for (int it = 0; it < 32; ++it) {
        int lin = it * 256 + tid;
        int kk = lin >> 6, c = lin & 63;
        Bs[kk][c] = cache[kk * TK_ + n0 + c];
    }
    __syncthreads();
    float acc[4][4] = {};
    for (int kk = 0; kk < 128; ++kk) {
        float4 a = *(const float4*)&As[kk][4 * tx];
        float4 b = *(const float4*)&Bs[kk][4 * ty];
        const float* ap = (const float*)&a;
        const float* bp = (const float*)&b;
        #pragma unroll
        for (int i = 0; i < 4; ++i)
            #pragma unroll
            for (int j = 0; j < 4; ++j) acc[i][j] += ap[i] * bp[j];
    }
    #pragma unroll
    for (int i = 0; i < 4; ++i) {
        int r = r0 + 4 * tx + i;
        #pragma unroll
        for (int j = 0; j < 4; ++j) {
            int n = n0 + 4 * ty + j;
            y[r * TK_ + n] = logits[r * TK_ + n] + 0.5f * acc[i][j];
        }
    }
}

// ---------------- K4b: em = (y @ W2 + b2), transposed write
__global__ __launch_bounds__(256) void gemm_em(const float* __restrict__ y,
    const float* __restrict__ W2q, const float* __restrict__ b2, float* __restrict__ em)
{
    int orig = blockIdx.x;
    int vb = (orig & 7) * 64 + (orig >> 3);
    int rb = vb >> 2, nq = vb & 3;
    int tid = threadIdx.x;
    int r = rb * 256 + tid;
    int c0 = nq * 19;
    const float* wq = W2q + nq * (74 * 20);
    const float* yrow = y + (size_t)r * 74;
    float acc[20];
    #pragma unroll
    for (int j = 0; j < 20; ++j) acc[j] = 0.f;
    #pragma unroll 1
    for (int k0 = 0; k0 < 74; k0 += 2) {
        float2 a = *(const float2*)(yrow + k0);
        const float* ap = (const float*)&a;
        #pragma unroll
        for (int u = 0; u < 2; ++u) {
            const float* wr = wq + (k0 + u) * 20;
            #pragma unroll
            for (int j = 0; j < 20; ++j) acc[j] += ap[u] * wr[j];
        }
    }
    int b = r >> 7, t = r & 127;
    #pragma unroll
    for (int j = 0; j < 19; ++j) {
        int c = c0 + j;
        if (c < 74) em[t * EMS_ + b * 74 + c] = acc[j] + b2[c];
    }
}

// ---------------- K5: fused CRF scans — ONE WAVE per sequence, zero barriers.
// Lane j owns state j; lanes 0..9 also own state 64+j. Viterbi: value-only fwd
// (full score history in LDS), wave-parallel argmax recompute in backtrace.
__global__ __launch_bounds__(64, 1) void crf_scan(const float* __restrict__ em,
    const int* __restrict__ mask_, const float* __restrict__ startv,
    const float* __restrict__ endv, const float* __restrict__ trans,
    float* __restrict__ out_tags, float* __restrict__ den)
{
    __shared__ float scoreAll[128][76] __attribute__((aligned(16)));  // Vit: rows 0..127; Norm: rows 2,3 = E dbuf
    __shared__ float transS[74 * 74];
    __shared__ int   maskS[128];
    int tid = threadIdx.x;          // 0..63
    bool isV = blockIdx.x < 256;
    int b = isV ? blockIdx.x : (blockIdx.x - 256);

    maskS[tid] = mask_[b * 128 + tid];
    maskS[64 + tid] = mask_[b * 128 + 64 + tid];
    for (int i = tid; i < 128; i += 64) { scoreAll[i][74] = -3.0e38f; scoreAll[i][75] = -3.0e38f; }
    if (isV) for (int i = tid; i < 74 * 74; i += 64) transS[i] = trans[i];

    const bool has2 = (tid < 10);
    const int j0 = tid;
    const int j1 = 64 + tid;
    const int j1c = has2 ? j1 : 0;   // clamped for global reads

    float tr0[76], tr1[76];
    #pragma unroll
    for (int k = 0; k < 74; ++k) tr0[k] = trans[k * 74 + j0];
    #pragma unroll
    for (int k = 0; k < 74; ++k) tr1[k] = trans[k * 74 + j1c];
    tr0[74] = tr0[75] = -1.0e30f;
    tr1[74] = tr1[75] = -1.0e30f;

    float prev0 = startv[j0] + em[b * 74 + j0];
    float prev1 = startv[j1c] + em[b * 74 + j1c];
    float eA0 = em[1 * EMS_ + b * 74 + j0];
    float eB0 = em[2 * EMS_ + b * 74 + j0];
    float eA1 = em[1 * EMS_ + b * 74 + j1c];
    float eB1 = em[2 * EMS_ + b * 74 + j1c];

    if (isV) {
        scoreAll[0][j0] = prev0;
        if (has2) scoreAll[0][j1] = prev1;
        WAVE_SYNC();
        for (int t = 1; t < 128; ++t) {
            float eC0 = 0.f, eC1 = 0.f;
            if (t + 2 < 128) {
                eC0 = em[(t + 2) * EMS_ + b * 74 + j0];
                eC1 = em[(t + 2) * EMS_ + b * 74 + j1c];
            }
            float m0 = -3.0e38f, m1 = -3.0e38f;
            #pragma unroll
            for (int kk = 0; kk < 19; ++kk) {
                float4 s4 = *(const float4*)&scoreAll[t - 1][4 * kk];
                m0 = fmaxf(fmaxf(m0, s4.x + tr0[4 * kk + 0]), s4.y + tr0[4 * kk + 1]);
                m0 = fmaxf(fmaxf(m0, s4.z + tr0[4 * kk + 2]), s4.w + tr0[4 * kk + 3]);
                m1 = fmaxf(fmaxf(m1, s4.x + tr1[4 * kk + 0]), s4.y + tr1[4 * kk + 1]);
                m1 = fmaxf(fmaxf(m1, s4.z + tr1[4 * kk + 2]), s4.w + tr1[4 * kk + 3]);
            }
            int mk = maskS[t];
            float snew0 = mk ? (m0 + eA0) : prev0;
            float snew1 = mk ? (m1 + eA1) : prev1;
            scoreAll[t][j0] = snew0;
            if (has2) scoreAll[t][j1] = snew1;
            prev0 = snew0; prev1 = snew1;
            WAVE_SYNC();
            eA0 = eB0; eB0 = eC0; eA1 = eB1; eB1 = eC1;
        }
        // best_last = argmax(score + endv), first-index ties
        float v = prev0 + endv[j0]; int mi = j0;
        if (has2) {
            float v1 = prev1 + endv[j1];
            if (v1 > v) { v = v1; mi = j1; }
        }
        #pragma unroll
        for (int off = 32; off > 0; off >>= 1) {
            float vo = __shfl_xor(v, off);
            int io = __shfl_xor(mi, off);
            if (vo > v || (vo == v && io < mi)) { v = vo; mi = io; }
        }
        int best = mi;
        if (tid == 0) out_tags[b * 128 + 127] = (float)best;
        int curk = best;
        for (int ti = 126; ti >= 0; --ti) {
            int mk = maskS[ti + 1];
            if (mk) {
                float vv = scoreAll[ti][j0] + transS[j0 * 74 + curk];
                int ii = j0;
                if (has2) {
                    float v1 = scoreAll[ti][j1] + transS[j1 * 74 + curk];
                    if (v1 > vv) { vv = v1; ii = j1; }
                }
                #pragma unroll
                for (int off = 32; off > 0; off >>= 1) {
                    float vo = __shfl_xor(vv, off);
                    int io = __shfl_xor(ii, off);
                    if (vo > vv || (vo == vv && io < ii)) { vv = vo; ii = io; }
                }
                curk = ii;
            } else {
                curk = best;
            }
            if (tid == 0) out_tags[b * 128 + ti] = (float)curk;
        }
    } else {
        // exp-factorized normalizer, E double-buffer in scoreAll rows 2,3
        #pragma unroll
        for (int k = 0; k < 76; ++k) tr0[k] = __expf(tr0[k]);
        #pragma unroll
        for (int k = 0; k < 76; ++k) tr1[k] = __expf(tr1[k]);   // pads -> 0
        // initial stabilizer M (wave max over score0)
        float v = prev0;
        if (has2) v = fmaxf(v, prev1);
        #pragma unroll
        for (int off = 32; off > 0; off >>= 1) v = fmaxf(v, __shfl_xor(v, off));
        float M = v;
        int cur = 0;
        scoreAll[2][j0] = __expf(prev0 - M);
        if (has2) scoreAll[2][j1] = __expf(prev1 - M);
        WAVE_SYNC();
        for (int t = 1; t < 128; ++t) {
            float eC0 = 0.f, eC1 = 0.f;
            if (t + 2 < 128) {
                eC0 = em[(t + 2) * EMS_ + b * 74 + j0];
                eC1 = em[(t + 2) * EMS_ + b * 74 + j1c];
            }
            float s0a = 0.f, s0b = 0.f, s1a = 0.f, s1b = 0.f;
            #pragma unroll
            for (int kk = 0; kk < 19; ++kk) {
                float4 E4 = *(const float4*)&scoreAll[2 + cur][4 * kk];
                s0a += E4.x * tr0[4 * kk + 0]; s0b += E4.y * tr0[4 * kk + 1];
                s0a += E4.z * tr0[4 * kk + 2]; s0b += E4.w * tr0[4 * kk + 3];
                s1a += E4.x * tr1[4 * kk + 0]; s1b += E4.y * tr1[4 * kk + 1];
                s1a += E4.z * tr1[4 * kk + 2]; s1b += E4.w * tr1[4 * kk + 3];
            }
            int mk = maskS[t];
            float nxt0 = M + __logf(s0a + s0b) + eA0;
            float nxt1 = M + __logf(s1a + s1b) + eA1;
            float snew0 = mk ? nxt0 : prev0;
            float snew1 = mk ? nxt1 : prev1;
            int over = (snew0 > M + 55.0f) || (has2 && (snew1 > M + 55.0f));
            int nund = (snew0 >= M - 40.0f) || (has2 && (snew1 >= M - 40.0f));
            if (__any(over) || !__any(nund)) {      // rare: refresh stabilizer
                float mv = snew0;
                if (has2) mv = fmaxf(mv, snew1);
                #pragma unroll
                for (int off = 32; off > 0; off >>= 1) mv = fmaxf(mv, __shfl_xor(mv, off));
                M = mv;
            }
            scoreAll[2 + (cur ^ 1)][j0] = __expf(snew0 - M);
            if (has2) scoreAll[2 + (cur ^ 1)][j1] = __expf(snew1 - M);
            prev0 = snew0; prev1 = snew1;
            WAVE_SYNC();
            cur ^= 1;
            eA0 = eB0; eB0 = eC0; eA1 = eB1; eB1 = eC1;
        }
        // final logsumexp over score + endv (in-register wave reduce)
        float f0 = prev0 + endv[j0];
        float f1 = has2 ? (prev1 + endv[j1]) : -3.0e38f;
        float mv = fmaxf(f0, f1);
        #pragma unroll
        for (int off = 32; off > 0; off >>= 1) mv = fmaxf(mv, __shfl_xor(mv, off));
        float s = __expf(f0 - mv) + (has2 ? __expf(f1 - mv) : 0.f);
        #pragma unroll
        for (int off = 32; off > 0; off >>= 1) s += __shfl_xor(s, off);
        if (tid == 0) den[b] = mv + __logf(s);
    }
}

// ---------------- K6: CRF score per batch, then final reduce
__global__ __launch_bounds__(128) void loss_partial(const float* __restrict__ em,
    const int* __restrict__ labels, const int* __restrict__ mask_,
    const float* __restrict__ startv, const float* __restrict__ endv,
    const float* __restrict__ den, const float* __restrict__ trans, float* __restrict__ nd)
{
    __shared__ float cs[2];
    __shared__ int ms[2];
    int b = blockIdx.x, t = threadIdx.x;
    int lab = labels[b * 128 + t];
    int mk = mask_[b * 128 + t];
    float contrib;
    if (t == 0) {
        contrib = startv[lab] + em[b * 74 + lab];
    } else {
        int labp = labels[b * 128 + t - 1];
        contrib = mk ? (trans[labp * 74 + lab] + em[t * EMS_ + b * 74 + lab]) : 0.f;
    }
    float c = contrib; int m = mk;
    #pragma unroll
    for (int off = 32; off > 0; off >>= 1) {
        c += __shfl_xor(c, off);
        m += __shfl_xor(m, off);
    }
    if ((t & 63) == 0) { cs[t >> 6] = c; ms[t >> 6] = m; }
    __syncthreads();
    if (t == 0) {
        float num = cs[0] + cs[1];
        int msum = ms[0] + ms[1];
        int last = labels[b * 128 + msum - 1];
        num += endv[last];
        nd[b] = num - den[b];
    }
}

__global__ void loss_final(const float* __restrict__ nd, float* __restrict__ out_loss)
{
    __shared__ float red[256];
    int i = threadIdx.x;
    red[i] = nd[i];
    __syncthreads();
    for (int s = 128; s > 0; s >>= 1) { if (i < s) red[i] += red[i + s]; __syncthreads(); }
    if (i == 0) out_loss[0] = -(red[0] / 256.f);
}

extern "C" void kernel_launch(void* const* d_in, const int* in_sizes, int n_in,
                              void* d_out, int out_size, void* d_ws, size_t ws_size,
                              hipStream_t stream)
{
    const float* feats  = (const float*)d_in[0];
    const int*   amask  = (const int*)d_in[1];
    const int*   labels = (const int*)d_in[2];
    const float* cache  = (const float*)d_in[3];
    const float* W1     = (const float*)d_in[4];
    const float* b1     = (const float*)d_in[5];
    const float* W2     = (const float*)d_in[6];
    const float* b2     = (const float*)d_in[7];
    const float* startv = (const float*)d_in[8];
    const float* endv   = (const float*)d_in[9];
    const float* trans  = (const float*)d_in[10];

    float* ws     = (float*)d_ws;
    float* logits = ws;                 // 2,424,832
    float* y      = ws + 2424832;       // 2,424,832 (doubles as K-split partial B)
    float* em     = ws + 4849664;       // 2,424,832
    float* part   = ws + 7274496;       // 1,048,576 (aliased by W1q until sim_partial)
    float* sim    = ws + 8323072;       // 32,768
    float* p      = ws + 8355840;       // 32,768
    float* den    = ws + 8388608;       // 256
    float* nd     = ws + 8388864;       // 256
    float* W2q    = ws + 8389120;       // 5,920
    float* W1q    = part;               // 61,440 — dead before sim_partial runs
    float* out_tags = (float*)d_out;
    float* out_loss = (float*)d_out + 32768;

    hipLaunchKernelGGL(pad_weights,      dim3(240),  dim3(256), 0, stream, W1, W2, W1q, W2q);
    hipLaunchKernelGGL(gemm_logits_part, dim3(1024), dim3(256), 0, stream, feats, W1q, logits, y);
    hipLaunchKernelGGL(logits_sum,       dim3(9472), dim3(256), 0, stream, y, b1, logits);
    hipLaunchKernelGGL(sim_partial,      dim3(256),  dim3(256), 0, stream, logits, cache, part);
    hipLaunchKernelGGL(sim_reduce,       dim3(128),  dim3(256), 0, stream, part, sim);
    hipLaunchKernelGGL(softmax128,       dim3(256),  dim3(128), 0, stream, sim, p);
    hipLaunchKernelGGL(gemm_h_y,         dim3(592),  dim3(256), 0, stream, p, cache, logits, y);
    hipLaunchKernelGGL(gemm_em,          dim3(512),  dim3(256), 0, stream, y, W2q, b2, em);
    hipLaunchKernelGGL(crf_scan,         dim3(512),  dim3(64),  0, stream, em, amask, startv, endv, trans, out_tags, den);
    hipLaunchKernelGGL(loss_partial,     dim3(256),  dim3(128), 0, stream, em, labels, amask, startv, endv, den, trans, nd);
    hipLaunchKernelGGL(loss_final,       dim3(1),    dim3(256), 0, stream, nd, out_loss);
}

// Round 11
// 277.776 us; speedup vs baseline: 1.2970x; 1.2970x over previous
//
#include <hip/hip_runtime.h>

#define B_ 256
#define T_ 128
#define D_ 768
#define K_ 74
#define C_ 128
#define TK_ 9472      // T_*K_
#define BT_ 32768     // B_*T_
#define EMS_ 18944    // B_*K_  (em time-slice stride)

#define LGKM_BARRIER() do { \
    asm volatile("s_waitcnt lgkmcnt(0)" ::: "memory"); \
    __builtin_amdgcn_s_barrier(); \
    __builtin_amdgcn_sched_barrier(0); \
} while (0)

// ---------------- K0: pad W1 -> W1q[4][768][20], W2 -> W2q[4][74][20]
__global__ void pad_weights(const float* __restrict__ W1, const float* __restrict__ W2,
                            float* __restrict__ W1q, float* __restrict__ W2q)
{
    int idx = blockIdx.x * 256 + threadIdx.x;
    if (idx < 4 * 768 * 20) {
        int nq = idx / (768 * 20); int rem = idx - nq * (768 * 20);
        int k = rem / 20, j = rem - k * 20;
        int c = nq * 19 + j;
        W1q[idx] = (j < 19 && c < 74) ? W1[k * 74 + c] : 0.f;
    }
    if (idx < 4 * 74 * 20) {
        int nq = idx / (74 * 20); int rem = idx - nq * (74 * 20);
        int k = rem / 20, j = rem - k * 20;
        int c = nq * 19 + j;
        W2q[idx] = (j < 19 && c < 74) ? W2[k * 74 + c] : 0.f;
    }
}

// ---------------- K1a: logits partials, K-split x2
__global__ __launch_bounds__(256) void gemm_logits_part(const float* __restrict__ feats,
    const float* __restrict__ W1q, float* __restrict__ outA, float* __restrict__ outB)
{
    int orig = blockIdx.x;                    // grid 1024
    int vb = (orig & 7) * 128 + (orig >> 3);
    int rb = vb >> 3, nq = (vb >> 1) & 3, ks = vb & 1;
    int tid = threadIdx.x;
    int r = rb * 256 + tid;
    int c0 = nq * 19;
    const float* frow = feats + (size_t)r * 768 + ks * 384;
    const float* wq = W1q + nq * (768 * 20) + ks * 384 * 20;
    float acc[20];
    #pragma unroll
    for (int j = 0; j < 20; ++j) acc[j] = 0.f;

    for (int k0 = 0; k0 < 384; k0 += 16) {
        float4 a[4];
        #pragma unroll
        for (int q = 0; q < 4; ++q) a[q] = *(const float4*)(frow + k0 + 4 * q);
        #pragma unroll
        for (int u = 0; u < 16; ++u) {
            float av = ((const float*)a)[u];
            const float* wr = wq + (k0 + u) * 20;
            #pragma unroll
            for (int j = 0; j < 20; ++j) acc[j] += av * wr[j];
        }
    }
    float* P = ks ? outB : outA;
    #pragma unroll
    for (int j = 0; j < 19; ++j) {
        int c = c0 + j;
        if (c < 74) P[(size_t)r * 74 + c] = acc[j];
    }
}

// ---------------- K1b: logits = A + B + b1
__global__ void logits_sum(const float* __restrict__ Bp, const float* __restrict__ b1,
                           float* __restrict__ logits)
{
    int idx = blockIdx.x * 256 + threadIdx.x;
    int r = idx / 74; int c = idx - r * 74;
    logits[idx] = logits[idx] + Bp[idx] + b1[c];
}

// ---------------- K2: sim partials
__global__ __launch_bounds__(256) void sim_partial(const float* __restrict__ logits,
    const float* __restrict__ cache, float* __restrict__ part)
{
    __shared__ float As[74][68];
    __shared__ float Bs[74][68];
    int tid = threadIdx.x;
    int tx = tid & 15, ty = tid >> 4;
    int bid = blockIdx.x;
    int jc = bid >> 3;
    int mt = (bid >> 1) & 3;
    int nt = bid & 1;
    int p0 = mt * 64, q0 = nt * 64;
    float acc[4][4] = {};
    for (int jj = 0; jj < 4; ++jj) {
        int j = jc * 4 + jj;
        for (int it = 0; it < 19; ++it) {
            int lin = it * 256 + tid;
            if (lin < 64 * 74) {
                int r = lin / 74, ik = lin - r * 74;
                As[ik][r] = logits[(p0 + r) * TK_ + j * 74 + ik];
                Bs[ik][r] = cache[(q0 + r) * TK_ + j * 74 + ik];
            }
        }
        __syncthreads();
        for (int ik = 0; ik < 74; ++ik) {
            float4 a = *(const float4*)&As[ik][4 * tx];
            float4 b = *(const float4*)&Bs[ik][4 * ty];
            const float* ap = (const float*)&a;
            const float* bp = (const float*)&b;
            #pragma unroll
            for (int i = 0; i < 4; ++i)
                #pragma unroll
                for (int q = 0; q < 4; ++q) acc[i][q] += ap[i] * bp[q];
        }
        __syncthreads();
    }
    #pragma unroll
    for (int i = 0; i < 4; ++i)
        #pragma unroll
        for (int q = 0; q < 4; ++q)
            part[jc * (B_ * C_) + (p0 + 4 * tx + i) * C_ + q0 + 4 * ty + q] = acc[i][q];
}

__global__ void sim_reduce(const float* __restrict__ part, float* __restrict__ sim)
{
    int idx = blockIdx.x * 256 + threadIdx.x;
    float s = 0.f;
    for (int jc = 0; jc < 32; ++jc) s += part[jc * (B_ * C_) + idx];
    sim[idx] = s;
}

__global__ void softmax128(const float* __restrict__ sim, float* __restrict__ p)
{
    __shared__ float red[128];
    int q = threadIdx.x, row = blockIdx.x;
    float v = sim[row * 128 + q];
    red[q] = v; __syncthreads();
    for (int s = 64; s > 0; s >>= 1) { if (q < s) red[q] = fmaxf(red[q], red[q + s]); __syncthreads(); }
    float m = red[0]; __syncthreads();
    float e = expf(v - m);
    red[q] = e; __syncthreads();
    for (int s = 64; s > 0; s >>= 1) { if (q < s) red[q] += red[q + s]; __syncthreads(); }
    float sum = red[0];
    p[row * 128 + q] = e / sum;
}

// ---------------- K4a: y = logits + 0.5*(p @ c_r)
__global__ __launch_bounds__(256) void gemm_h_y(const float* __restrict__ pmat,
    const float* __restrict__ cache, const float* __restrict__ logits, float* __restrict__ y)
{
    __shared__ float As[128][68];
    __shared__ float Bs[128][68];
    int tid = threadIdx.x;
    int tx = tid & 15, ty = tid >> 4;
    int mt = blockIdx.x / 148, nt = blockIdx.x - mt * 148;
    int r0 = mt * 64, n0 = nt * 64;
    #pragma unroll
    for (int it = 0; it < 32; ++it) {
        int lin = it * 256 + tid;
        int r = lin >> 7, kk = lin & 127;
        As[kk][r] = pmat[(r0 + r) * 128 + kk];
    }
    #pragma unroll
    for (int it = 0; it < 32; ++it) {
        int lin = it * 256 + tid;
        int kk = lin >> 6, c = lin & 63;
        Bs[kk][c] = cache[kk * TK_ + n0 + c];
    }
    __syncthreads();
    float acc[4][4] = {};
    for (int kk = 0; kk < 128; ++kk) {
        float4 a = *(const float4*)&As[kk][4 * tx];
        float4 b = *(const float4*)&Bs[kk][4 * ty];
        const float* ap = (const float*)&a;
        const float* bp = (const float*)&b;
        #pragma unroll
        for (int i = 0; i < 4; ++i)
            #pragma unroll
            for (int j = 0; j < 4; ++j) acc[i][j] += ap[i] * bp[j];
    }
    #pragma unroll
    for (int i = 0; i < 4; ++i) {
        int r = r0 + 4 * tx + i;
        #pragma unroll
        for (int j = 0; j < 4; ++j) {
            int n = n0 + 4 * ty + j;
            y[r * TK_ + n] = logits[r * TK_ + n] + 0.5f * acc[i][j];
        }
    }
}

// ---------------- K4b: em = (y @ W2 + b2), transposed write
__global__ __launch_bounds__(256) void gemm_em(const float* __restrict__ y,
    const float* __restrict__ W2q, const float* __restrict__ b2, float* __restrict__ em)
{
    int orig = blockIdx.x;
    int vb = (orig & 7) * 64 + (orig >> 3);
    int rb = vb >> 2, nq = vb & 3;
    int tid = threadIdx.x;
    int r = rb * 256 + tid;
    int c0 = nq * 19;
    const float* wq = W2q + nq * (74 * 20);
    const float* yrow = y + (size_t)r * 74;
    float acc[20];
    #pragma unroll
    for (int j = 0; j < 20; ++j) acc[j] = 0.f;
    #pragma unroll 1
    for (int k0 = 0; k0 < 74; k0 += 2) {
        float2 a = *(const float2*)(yrow + k0);
        const float* ap = (const float*)&a;
        #pragma unroll
        for (int u = 0; u < 2; ++u) {
            const float* wr = wq + (k0 + u) * 20;
            #pragma unroll
            for (int j = 0; j < 20; ++j) acc[j] += ap[u] * wr[j];
        }
    }
    int b = r >> 7, t = r & 127;
    #pragma unroll
    for (int j = 0; j < 19; ++j) {
        int c = c0 + j;
        if (c < 74) em[t * EMS_ + b * 74 + c] = acc[j] + b2[c];
    }
}

// ---------------- K5: fused CRF scans (R8 topology). Viterbi: 2-chain argmax.
// Normalizer: linear-domain E recursion, power-of-two rescale counter, no per-step log.
__global__ __launch_bounds__(256) void crf_scan(const float* __restrict__ em,
    const int* __restrict__ mask_, const float* __restrict__ startv,
    const float* __restrict__ endv, const float* __restrict__ trans,
    float* __restrict__ out_tags, float* __restrict__ den)
{
    __shared__ float transS[74 * 74];
    __shared__ float scoreS[2][88];
    __shared__ float EscS[2][88] __attribute__((aligned(16)));
    __shared__ float pv[3][74];
    __shared__ int   pi[3][74];
    __shared__ unsigned char histS[127 * 74];
    __shared__ float tagsS[128];
    __shared__ float Ms[2];
    __shared__ int   flagU[2];
    __shared__ int   maskS[128];
    int tid = threadIdx.x;
    bool isV = blockIdx.x < 256;
    int b = isV ? blockIdx.x : (blockIdx.x - 256);

    for (int i = tid; i < 74 * 74; i += 256) transS[i] = trans[i];
    if (tid < 128) maskS[tid] = mask_[b * 128 + tid];
    if (tid >= 74 && tid < 88) {
        scoreS[0][tid] = -3.0e38f; scoreS[1][tid] = -3.0e38f;
        EscS[0][tid] = 0.f;        EscS[1][tid] = 0.f;
    }
    if (tid < 74) scoreS[0][tid] = startv[tid] + em[b * 74 + tid];
    __syncthreads();

    int ch = (tid < 74) ? 0 : (tid < 148 ? 1 : 2);   // 3 chunks of 28 sources
    int kp = tid - ch * 74;                          // dest state
    int cbase = ch * 28;
    float tr[28];
    if (tid < 222) {
        #pragma unroll
        for (int j = 0; j < 28; ++j) {
            int kk = cbase + j;
            tr[j] = (kk < 74) ? transS[kk * 74 + kp] : -1.0e30f;
        }
    }
    int cur = 0;

    // depth-2 em prefetch registers
    float eA = 0.f, eB = 0.f;
    if (tid < 74) {
        eA = em[1 * EMS_ + b * 74 + tid];
        eB = em[2 * EMS_ + b * 74 + tid];
    }

    if (isV) {
        for (int t = 1; t < 128; ++t) {
            float eC = 0.f;
            if (tid < 74 && t + 2 < 128) eC = em[(t + 2) * EMS_ + b * 74 + tid];
            if (tid < 222) {
                float mA = -3.0e38f; int iA = cbase;
                float mB = -3.0e38f; int iB = cbase + 12;
                #pragma unroll
                for (int jj = 0; jj < 3; ++jj) {
                    float4 s4 = *(const float4*)&scoreS[cur][cbase + 4 * jj];
                    const float* sp = (const float*)&s4;
                    #pragma unroll
                    for (int u = 0; u < 4; ++u) {
                        float v = sp[u] + tr[4 * jj + u];
                        if (v > mA) { mA = v; iA = cbase + 4 * jj + u; }
                    }
                }
                #pragma unroll
                for (int jj = 3; jj < 7; ++jj) {
                    float4 s4 = *(const float4*)&scoreS[cur][cbase + 4 * jj];
                    const float* sp = (const float*)&s4;
                    #pragma unroll
                    for (int u = 0; u < 4; ++u) {
                        float v = sp[u] + tr[4 * jj + u];
                        if (v > mB) { mB = v; iB = cbase + 4 * jj + u; }
                    }
                }
                float m; int mi;
                if (mB > mA) { m = mB; mi = iB; } else { m = mA; mi = iA; }
                pv[ch][kp] = m; pi[ch][kp] = mi;
            }
            LGKM_BARRIER();
            int mk = maskS[t];
            if (tid < 74) {
                float m0 = pv[0][tid]; int i0 = pi[0][tid];
                if (pv[1][tid] > m0) { m0 = pv[1][tid]; i0 = pi[1][tid]; }
                if (pv[2][tid] > m0) { m0 = pv[2][tid]; i0 = pi[2][tid]; }
                histS[(t - 1) * 74 + tid] = (unsigned char)i0;
                scoreS[cur ^ 1][tid] = mk ? (m0 + eA) : scoreS[cur][tid];
            }
            LGKM_BARRIER();
            cur ^= 1;
            eA = eB; eB = eC;
        }
        if (tid == 0) {
            float bm = scoreS[cur][0] + endv[0]; int bi = 0;
            for (int k = 1; k < 74; ++k) {
                float v = scoreS[cur][k] + endv[k];
                if (v > bm) { bm = v; bi = k; }
            }
            int curk = bi;
            tagsS[127] = (float)bi;
            for (int ti = 126; ti >= 0; --ti) {
                int mk = maskS[ti + 1];
                curk = mk ? (int)histS[ti * 74 + curk] : bi;
                tagsS[ti] = (float)curk;
            }
        }
        __syncthreads();
        if (tid < 128) out_tags[b * 128 + tid] = tagsS[tid];
    } else {
        // tr regs hold exp(trans); pads exp(-1e30) = 0 (identity for sums)
        if (tid < 222) {
            #pragma unroll
            for (int j = 0; j < 28; ++j) tr[j] = __expf(tr[j]);
        }
        // initial stabilizer M (exact), then linear-domain recursion
        float v0 = (tid < 74) ? scoreS[0][tid] : -3.0e38f;
        float M;
        if (tid < 128) {
            #pragma unroll
            for (int off = 32; off > 0; off >>= 1) v0 = fmaxf(v0, __shfl_xor(v0, off));
            if ((tid & 63) == 0) Ms[tid >> 6] = v0;
        }
        __syncthreads();
        M = fmaxf(Ms[0], Ms[1]);
        if (tid < 74) EscS[0][tid] = __expf(scoreS[0][tid] - M);
        int count = 0;
        LGKM_BARRIER();
        for (int t = 1; t < 128; ++t) {
            float eC = 0.f;
            if (tid < 74 && t + 2 < 128) eC = em[(t + 2) * EMS_ + b * 74 + tid];
            if (tid < 222) {
                float s0 = 0.f, s1 = 0.f, s2 = 0.f, s3 = 0.f;
                #pragma unroll
                for (int jj = 0; jj < 7; ++jj) {
                    float4 E4 = *(const float4*)&EscS[cur][cbase + 4 * jj];
                    s0 += E4.x * tr[4 * jj + 0];
                    s1 += E4.y * tr[4 * jj + 1];
                    s2 += E4.z * tr[4 * jj + 2];
                    s3 += E4.w * tr[4 * jj + 3];
                }
                pv[ch][kp] = (s0 + s1) + (s2 + s3);
            }
            LGKM_BARRIER();
            int mk = maskS[t];
            int over = 0, notsmall = 0;
            if (tid < 74) {
                float u = pv[0][tid] + pv[1][tid] + pv[2][tid];
                float un = u * __expf(eA);
                float En = mk ? un : EscS[cur][tid];
                EscS[cur ^ 1][tid] = En;
                over = (En > 0x1p64f) ? 1 : 0;
                notsmall = (En >= 0x1p-32f) ? 1 : 0;
            }
            int wOver = __any(over) ? 1 : 0;
            int wNs = __any(notsmall) ? 2 : 0;
            if ((tid & 63) == 0 && tid < 128) flagU[tid >> 6] = wOver | wNs;
            LGKM_BARRIER();
            cur ^= 1;
            int fl = flagU[0] | flagU[1];
            if (fl & 1) {                        // overflow: exact /2^64
                if (tid < 74) EscS[cur][tid] *= 0x1p-64f;
                count++;
                LGKM_BARRIER();
            } else if (!(fl & 2)) {              // underflow: exact *2^64
                if (tid < 74) EscS[cur][tid] *= 0x1p64f;
                count--;
                LGKM_BARRIER();
            }
            eA = eB; eB = eC;
        }
        if (tid == 0) {
            float s = 0.f;
            for (int k = 0; k < 74; ++k) s += EscS[cur][k] * __expf(endv[k]);
            den[b] = M + (float)count * 44.36141955583650f + __logf(s);
        }
    }
}

// ---------------- K6: CRF score per batch, then final reduce
__global__ __launch_bounds__(128) void loss_partial(const float* __restrict__ em,
    const int* __restrict__ labels, const int* __restrict__ mask_,
    const float* __restrict__ startv, const float* __restrict__ endv,
    const float* __restrict__ den, const float* __restrict__ trans, float* __restrict__ nd)
{
    __shared__ float cs[2];
    __shared__ int ms[2];
    int b = blockIdx.x, t = threadIdx.x;
    int lab = labels[b * 128 + t];
    int mk = mask_[b * 128 + t];
    float contrib;
    if (t == 0) {
        contrib = startv[lab] + em[b * 74 + lab];
    } else {
        int labp = labels[b * 128 + t - 1];
        contrib = mk ? (trans[labp * 74 + lab] + em[t * EMS_ + b * 74 + lab]) : 0.f;
    }
    float c = contrib; int m = mk;
    #pragma unroll
    for (int off = 32; off > 0; off >>= 1) {
        c += __shfl_xor(c, off);
        m += __shfl_xor(m, off);
    }
    if ((t & 63) == 0) { cs[t >> 6] = c; ms[t >> 6] = m; }
    __syncthreads();
    if (t == 0) {
        float num = cs[0] + cs[1];
        int msum = ms[0] + ms[1];
        int last = labels[b * 128 + msum - 1];
        num += endv[last];
        nd[b] = num - den[b];
    }
}

__global__ void loss_final(const float* __restrict__ nd, float* __restrict__ out_loss)
{
    __shared__ float red[256];
    int i = threadIdx.x;
    red[i] = nd[i];
    __syncthreads();
    for (int s = 128; s > 0; s >>= 1) { if (i < s) red[i] += red[i + s]; __syncthreads(); }
    if (i == 0) out_loss[0] = -(red[0] / 256.f);
}

extern "C" void kernel_launch(void* const* d_in, const int* in_sizes, int n_in,
                              void* d_out, int out_size, void* d_ws, size_t ws_size,
                              hipStream_t stream)
{
    const float* feats  = (const float*)d_in[0];
    const int*   amask  = (const int*)d_in[1];
    const int*   labels = (const int*)d_in[2];
    const float* cache  = (const float*)d_in[3];
    const float* W1     = (const float*)d_in[4];
    const float* b1     = (const float*)d_in[5];
    const float* W2     = (const float*)d_in[6];
    const float* b2     = (const float*)d_in[7];
    const float* startv = (const float*)d_in[8];
    const float* endv   = (const float*)d_in[9];
    const float* trans  = (const float*)d_in[10];

    float* ws     = (float*)d_ws;
    float* logits = ws;                 // 2,424,832
    float* y      = ws + 2424832;       // 2,424,832 (doubles as K-split partial B)
    float* em     = ws + 4849664;       // 2,424,832
    float* part   = ws + 7274496;       // 1,048,576 (aliased by W1q until sim_partial)
    float* sim    = ws + 8323072;       // 32,768
    float* p      = ws + 8355840;       // 32,768
    float* den    = ws + 8388608;       // 256
    float* nd     = ws + 8388864;       // 256
    float* W2q    = ws + 8389120;       // 5,920
    float* W1q    = part;               // 61,440 — dead before sim_partial runs
    float* out_tags = (float*)d_out;
    float* out_loss = (float*)d_out + 32768;

    hipLaunchKernelGGL(pad_weights,      dim3(240),  dim3(256), 0, stream, W1, W2, W1q, W2q);
    hipLaunchKernelGGL(gemm_logits_part, dim3(1024), dim3(256), 0, stream, feats, W1q, logits, y);
    hipLaunchKernelGGL(logits_sum,       dim3(9472), dim3(256), 0, stream, y, b1, logits);
    hipLaunchKernelGGL(sim_partial,      dim3(256),  dim3(256), 0, stream, logits, cache, part);
    hipLaunchKernelGGL(sim_reduce,       dim3(128),  dim3(256), 0, stream, part, sim);
    hipLaunchKernelGGL(softmax128,       dim3(256),  dim3(128), 0, stream, sim, p);
    hipLaunchKernelGGL(gemm_h_y,         dim3(592),  dim3(256), 0, stream, p, cache, logits, y);
    hipLaunchKernelGGL(gemm_em,          dim3(512),  dim3(256), 0, stream, y, W2q, b2, em);
    hipLaunchKernelGGL(crf_scan,         dim3(512),  dim3(256), 0, stream, em, amask, startv, endv, trans, out_tags, den);
    hipLaunchKernelGGL(loss_partial,     dim3(256),  dim3(128), 0, stream, em, labels, amask, startv, endv, den, trans, nd);
    hipLaunchKernelGGL(loss_final,       dim3(1),    dim3(256), 0, stream, nd, out_loss);
}

// Round 12
// 253.644 us; speedup vs baseline: 1.4204x; 1.0951x over previous
//
#include <hip/hip_runtime.h>

#define B_ 256
#define T_ 128
#define D_ 768
#define K_ 74
#define C_ 128
#define TK_ 9472      // T_*K_
#define BT_ 32768     // B_*T_
#define EMS_ 18944    // B_*K_  (em time-slice stride)

#define LGKM_BARRIER() do { \
    asm volatile("s_waitcnt lgkmcnt(0)" ::: "memory"); \
    __builtin_amdgcn_s_barrier(); \
    __builtin_amdgcn_sched_barrier(0); \
} while (0)

// ---------------- K0: pad W1 -> W1q[4][768][20], W2 -> W2q[4][74][20]
__global__ void pad_weights(const float* __restrict__ W1, const float* __restrict__ W2,
                            float* __restrict__ W1q, float* __restrict__ W2q)
{
    int idx = blockIdx.x * 256 + threadIdx.x;
    if (idx < 4 * 768 * 20) {
        int nq = idx / (768 * 20); int rem = idx - nq * (768 * 20);
        int k = rem / 20, j = rem - k * 20;
        int c = nq * 19 + j;
        W1q[idx] = (j < 19 && c < 74) ? W1[k * 74 + c] : 0.f;
    }
    if (idx < 4 * 74 * 20) {
        int nq = idx / (74 * 20); int rem = idx - nq * (74 * 20);
        int k = rem / 20, j = rem - k * 20;
        int c = nq * 19 + j;
        W2q[idx] = (j < 19 && c < 74) ? W2[k * 74 + c] : 0.f;
    }
}

// ---------------- K1a: logits partials, K-split x2
__global__ __launch_bounds__(256) void gemm_logits_part(const float* __restrict__ feats,
    const float* __restrict__ W1q, float* __restrict__ outA, float* __restrict__ outB)
{
    int orig = blockIdx.x;                    // grid 1024
    int vb = (orig & 7) * 128 + (orig >> 3);
    int rb = vb >> 3, nq = (vb >> 1) & 3, ks = vb & 1;
    int tid = threadIdx.x;
    int r = rb * 256 + tid;
    int c0 = nq * 19;
    const float* frow = feats + (size_t)r * 768 + ks * 384;
    const float* wq = W1q + nq * (768 * 20) + ks * 384 * 20;
    float acc[20];
    #pragma unroll
    for (int j = 0; j < 20; ++j) acc[j] = 0.f;

    for (int k0 = 0; k0 < 384; k0 += 16) {
        float4 a[4];
        #pragma unroll
        for (int q = 0; q < 4; ++q) a[q] = *(const float4*)(frow + k0 + 4 * q);
        #pragma unroll
        for (int u = 0; u < 16; ++u) {
            float av = ((const float*)a)[u];
            const float* wr = wq + (k0 + u) * 20;
            #pragma unroll
            for (int j = 0; j < 20; ++j) acc[j] += av * wr[j];
        }
    }
    float* P = ks ? outB : outA;
    #pragma unroll
    for (int j = 0; j < 19; ++j) {
        int c = c0 + j;
        if (c < 74) P[(size_t)r * 74 + c] = acc[j];
    }
}

// ---------------- K1b: logits = A + B + b1
__global__ void logits_sum(const float* __restrict__ Bp, const float* __restrict__ b1,
                           float* __restrict__ logits)
{
    int idx = blockIdx.x * 256 + threadIdx.x;
    int r = idx / 74; int c = idx - r * 74;
    logits[idx] = logits[idx] + Bp[idx] + b1[c];
}

// ---------------- K2: sim partials — 64 j-chunks (2 planes each), grid 512
__global__ __launch_bounds__(256) void sim_partial(const float* __restrict__ logits,
    const float* __restrict__ cache, float* __restrict__ part)
{
    __shared__ float As[74][68];
    __shared__ float Bs[74][68];
    int tid = threadIdx.x;
    int tx = tid & 15, ty = tid >> 4;
    int bid = blockIdx.x;                 // 512 = 64 jc x 4 mt x 2 nt
    int jc = bid >> 3;
    int mt = (bid >> 1) & 3;
    int nt = bid & 1;
    int p0 = mt * 64, q0 = nt * 64;
    float acc[4][4] = {};
    for (int jj = 0; jj < 2; ++jj) {
        int j = jc * 2 + jj;
        for (int it = 0; it < 19; ++it) {
            int lin = it * 256 + tid;
            if (lin < 64 * 74) {
                int r = lin / 74, ik = lin - r * 74;
                As[ik][r] = logits[(p0 + r) * TK_ + j * 74 + ik];
                Bs[ik][r] = cache[(q0 + r) * TK_ + j * 74 + ik];
            }
        }
        __syncthreads();
        for (int ik = 0; ik < 74; ++ik) {
            float4 a = *(const float4*)&As[ik][4 * tx];
            float4 b = *(const float4*)&Bs[ik][4 * ty];
            const float* ap = (const float*)&a;
            const float* bp = (const float*)&b;
            #pragma unroll
            for (int i = 0; i < 4; ++i)
                #pragma unroll
                for (int q = 0; q < 4; ++q) acc[i][q] += ap[i] * bp[q];
        }
        __syncthreads();
    }
    #pragma unroll
    for (int i = 0; i < 4; ++i)
        #pragma unroll
        for (int q = 0; q < 4; ++q)
            part[jc * (B_ * C_) + (p0 + 4 * tx + i) * C_ + q0 + 4 * ty + q] = acc[i][q];
}

__global__ void sim_reduce(const float* __restrict__ part, float* __restrict__ sim)
{
    int idx = blockIdx.x * 256 + threadIdx.x;
    float s = 0.f;
    for (int jc = 0; jc < 64; ++jc) s += part[jc * (B_ * C_) + idx];
    sim[idx] = s;
}

__global__ void softmax128(const float* __restrict__ sim, float* __restrict__ p)
{
    __shared__ float red[128];
    int q = threadIdx.x, row = blockIdx.x;
    float v = sim[row * 128 + q];
    red[q] = v; __syncthreads();
    for (int s = 64; s > 0; s >>= 1) { if (q < s) red[q] = fmaxf(red[q], red[q + s]); __syncthreads(); }
    float m = red[0]; __syncthreads();
    float e = expf(v - m);
    red[q] = e; __syncthreads();
    for (int s = 64; s > 0; s >>= 1) { if (q < s) red[q] += red[q + s]; __syncthreads(); }
    float sum = red[0];
    p[row * 128 + q] = e / sum;
}

// ---------------- K4a: y = logits + 0.5*(p @ c_r) — two K=64 stages (35KB LDS, 4 blk/CU)
__global__ __launch_bounds__(256) void gemm_h_y(const float* __restrict__ pmat,
    const float* __restrict__ cache, const float* __restrict__ logits, float* __restrict__ y)
{
    __shared__ float As[64][68];
    __shared__ float Bs[64][68];
    int tid = threadIdx.x;
    int tx = tid & 15, ty = tid >> 4;
    int orig = blockIdx.x;                 // 592 = 8 x 74, bijective XCD swizzle
    int vb = (orig & 7) * 74 + (orig >> 3);
    int mt = vb / 148, nt = vb - mt * 148;
    int r0 = mt * 64, n0 = nt * 64;
    float acc[4][4] = {};
    #pragma unroll
    for (int s = 0; s < 2; ++s) {
        #pragma unroll
        for (int it = 0; it < 16; ++it) {
            int lin = it * 256 + tid;
            int r = lin >> 6, kk = lin & 63;
            As[kk][r] = pmat[(r0 + r) * 128 + s * 64 + kk];
        }
        #pragma unroll
        for (int it = 0; it < 16; ++it) {
            int lin = it * 256 + tid;
            int kk = lin >> 6, c = lin & 63;
            Bs[kk][c] = cache[(s * 64 + kk) * TK_ + n0 + c];
        }
        __syncthreads();
        for (int kk = 0; kk < 64; ++kk) {
            float4 a = *(const float4*)&As[kk][4 * tx];
            float4 b = *(const float4*)&Bs[kk][4 * ty];
            const float* ap = (const float*)&a;
            const float* bp = (const float*)&b;
            #pragma unroll
            for (int i = 0; i < 4; ++i)
                #pragma unroll
                for (int j = 0; j < 4; ++j) acc[i][j] += ap[i] * bp[j];
        }
        __syncthreads();
    }
    #pragma unroll
    for (int i = 0; i < 4; ++i) {
        int r = r0 + 4 * tx + i;
        #pragma unroll
        for (int j = 0; j < 4; ++j) {
            int n = n0 + 4 * ty + j;
            y[r * TK_ + n] = logits[r * TK_ + n] + 0.5f * acc[i][j];
        }
    }
}

// ---------------- K4b: em = (y @ W2 + b2), transposed write
__global__ __launch_bounds__(256) void gemm_em(const float* __restrict__ y,
    const float* __restrict__ W2q, const float* __restrict__ b2, float* __restrict__ em)
{
    int orig = blockIdx.x;
    int vb = (orig & 7) * 64 + (orig >> 3);
    int rb = vb >> 2, nq = vb & 3;
    int tid = threadIdx.x;
    int r = rb * 256 + tid;
    int c0 = nq * 19;
    const float* wq = W2q + nq * (74 * 20);
    const float* yrow = y + (size_t)r * 74;
    float acc[20];
    #pragma unroll
    for (int j = 0; j < 20; ++j) acc[j] = 0.f;
    #pragma unroll 1
    for (int k0 = 0; k0 < 74; k0 += 2) {
        float2 a = *(const float2*)(yrow + k0);
        const float* ap = (const float*)&a;
        #pragma unroll
        for (int u = 0; u < 2; ++u) {
            const float* wr = wq + (k0 + u) * 20;
            #pragma unroll
            for (int j = 0; j < 20; ++j) acc[j] += ap[u] * wr[j];
        }
    }
    int b = r >> 7, t = r & 127;
    #pragma unroll
    for (int j = 0; j < 19; ++j) {
        int c = c0 + j;
        if (c < 74) em[t * EMS_ + b * 74 + c] = acc[j] + b2[c];
    }
}

// ---------------- K5: fused CRF scans (R8 topology). Viterbi: 2-chain argmax.
// Normalizer: linear-domain E recursion, power-of-two rescale counter.
__global__ __launch_bounds__(256) void crf_scan(const float* __restrict__ em,
    const int* __restrict__ mask_, const float* __restrict__ startv,
    const float* __restrict__ endv, const float* __restrict__ trans,
    float* __restrict__ out_tags, float* __restrict__ den)
{
    __shared__ float transS[74 * 74];
    __shared__ float scoreS[2][88];
    __shared__ float EscS[2][88] __attribute__((aligned(16)));
    __shared__ float pv[3][74];
    __shared__ int   pi[3][74];
    __shared__ unsigned char histS[127 * 74];
    __shared__ float tagsS[128];
    __shared__ float Ms[2];
    __shared__ int   flagU[2];
    __shared__ int   maskS[128];
    int tid = threadIdx.x;
    bool isV = blockIdx.x < 256;
    int b = isV ? blockIdx.x : (blockIdx.x - 256);

    for (int i = tid; i < 74 * 74; i += 256) transS[i] = trans[i];
    if (tid < 128) maskS[tid] = mask_[b * 128 + tid];
    if (tid >= 74 && tid < 88) {
        scoreS[0][tid] = -3.0e38f; scoreS[1][tid] = -3.0e38f;
        EscS[0][tid] = 0.f;        EscS[1][tid] = 0.f;
    }
    if (tid < 74) scoreS[0][tid] = startv[tid] + em[b * 74 + tid];
    __syncthreads();

    int ch = (tid < 74) ? 0 : (tid < 148 ? 1 : 2);   // 3 chunks of 28 sources
    int kp = tid - ch * 74;                          // dest state
    int cbase = ch * 28;
    float tr[28];
    if (tid < 222) {
        #pragma unroll
        for (int j = 0; j < 28; ++j) {
            int kk = cbase + j;
            tr[j] = (kk < 74) ? transS[kk * 74 + kp] : -1.0e30f;
        }
    }
    int cur = 0;

    float eA = 0.f, eB = 0.f;
    if (tid < 74) {
        eA = em[1 * EMS_ + b * 74 + tid];
        eB = em[2 * EMS_ + b * 74 + tid];
    }

    if (isV) {
        for (int t = 1; t < 128; ++t) {
            float eC = 0.f;
            if (tid < 74 && t + 2 < 128) eC = em[(t + 2) * EMS_ + b * 74 + tid];
            if (tid < 222) {
                float mA = -3.0e38f; int iA = cbase;
                float mB = -3.0e38f; int iB = cbase + 12;
                #pragma unroll
                for (int jj = 0; jj < 3; ++jj) {
                    float4 s4 = *(const float4*)&scoreS[cur][cbase + 4 * jj];
                    const float* sp = (const float*)&s4;
                    #pragma unroll
                    for (int u = 0; u < 4; ++u) {
                        float v = sp[u] + tr[4 * jj + u];
                        if (v > mA) { mA = v; iA = cbase + 4 * jj + u; }
                    }
                }
                #pragma unroll
                for (int jj = 3; jj < 7; ++jj) {
                    float4 s4 = *(const float4*)&scoreS[cur][cbase + 4 * jj];
                    const float* sp = (const float*)&s4;
                    #pragma unroll
                    for (int u = 0; u < 4; ++u) {
                        float v = sp[u] + tr[4 * jj + u];
                        if (v > mB) { mB = v; iB = cbase + 4 * jj + u; }
                    }
                }
                float m; int mi;
                if (mB > mA) { m = mB; mi = iB; } else { m = mA; mi = iA; }
                pv[ch][kp] = m; pi[ch][kp] = mi;
            }
            LGKM_BARRIER();
            int mk = maskS[t];
            if (tid < 74) {
                float m0 = pv[0][tid]; int i0 = pi[0][tid];
                if (pv[1][tid] > m0) { m0 = pv[1][tid]; i0 = pi[1][tid]; }
                if (pv[2][tid] > m0) { m0 = pv[2][tid]; i0 = pi[2][tid]; }
                histS[(t - 1) * 74 + tid] = (unsigned char)i0;
                scoreS[cur ^ 1][tid] = mk ? (m0 + eA) : scoreS[cur][tid];
            }
            LGKM_BARRIER();
            cur ^= 1;
            eA = eB; eB = eC;
        }
        if (tid == 0) {
            float bm = scoreS[cur][0] + endv[0]; int bi = 0;
            for (int k = 1; k < 74; ++k) {
                float v = scoreS[cur][k] + endv[k];
                if (v > bm) { bm = v; bi = k; }
            }
            int curk = bi;
            tagsS[127] = (float)bi;
            for (int ti = 126; ti >= 0; --ti) {
                int mk = maskS[ti + 1];
                curk = mk ? (int)histS[ti * 74 + curk] : bi;
                tagsS[ti] = (float)curk;
            }
        }
        __syncthreads();
        if (tid < 128) out_tags[b * 128 + tid] = tagsS[tid];
    } else {
        if (tid < 222) {
            #pragma unroll
            for (int j = 0; j < 28; ++j) tr[j] = __expf(tr[j]);
        }
        float v0 = (tid < 74) ? scoreS[0][tid] : -3.0e38f;
        float M;
        if (tid < 128) {
            #pragma unroll
            for (int off = 32; off > 0; off >>= 1) v0 = fmaxf(v0, __shfl_xor(v0, off));
            if ((tid & 63) == 0) Ms[tid >> 6] = v0;
        }
        __syncthreads();
        M = fmaxf(Ms[0], Ms[1]);
        if (tid < 74) EscS[0][tid] = __expf(scoreS[0][tid] - M);
        int count = 0;
        LGKM_BARRIER();
        for (int t = 1; t < 128; ++t) {
            float eC = 0.f;
            if (tid < 74 && t + 2 < 128) eC = em[(t + 2) * EMS_ + b * 74 + tid];
            if (tid < 222) {
                float s0 = 0.f, s1 = 0.f, s2 = 0.f, s3 = 0.f;
                #pragma unroll
                for (int jj = 0; jj < 7; ++jj) {
                    float4 E4 = *(const float4*)&EscS[cur][cbase + 4 * jj];
                    s0 += E4.x * tr[4 * jj + 0];
                    s1 += E4.y * tr[4 * jj + 1];
                    s2 += E4.z * tr[4 * jj + 2];
                    s3 += E4.w * tr[4 * jj + 3];
                }
                pv[ch][kp] = (s0 + s1) + (s2 + s3);
            }
            LGKM_BARRIER();
            int mk = maskS[t];
            int over = 0, notsmall = 0;
            if (tid < 74) {
                float u = pv[0][tid] + pv[1][tid] + pv[2][tid];
                float un = u * __expf(eA);
                float En = mk ? un : EscS[cur][tid];
                EscS[cur ^ 1][tid] = En;
                over = (En > 0x1p64f) ? 1 : 0;
                notsmall = (En >= 0x1p-32f) ? 1 : 0;
            }
            int wOver = __any(over) ? 1 : 0;
            int wNs = __any(notsmall) ? 2 : 0;
            if ((tid & 63) == 0 && tid < 128) flagU[tid >> 6] = wOver | wNs;
            LGKM_BARRIER();
            cur ^= 1;
            int fl = flagU[0] | flagU[1];
            if (fl & 1) {
                if (tid < 74) EscS[cur][tid] *= 0x1p-64f;
                count++;
                LGKM_BARRIER();
            } else if (!(fl & 2)) {
                if (tid < 74) EscS[cur][tid] *= 0x1p64f;
                count--;
                LGKM_BARRIER();
            }
            eA = eB; eB = eC;
        }
        if (tid == 0) {
            float s = 0.f;
            for (int k = 0; k < 74; ++k) s += EscS[cur][k] * __expf(endv[k]);
            den[b] = M + (float)count * 44.36141955583650f + __logf(s);
        }
    }
}

// ---------------- K6: CRF score per batch, then final reduce
__global__ __launch_bounds__(128) void loss_partial(const float* __restrict__ em,
    const int* __restrict__ labels, const int* __restrict__ mask_,
    const float* __restrict__ startv, const float* __restrict__ endv,
    const float* __restrict__ den, const float* __restrict__ trans, float* __restrict__ nd)
{
    __shared__ float cs[2];
    __shared__ int ms[2];
    int b = blockIdx.x, t = threadIdx.x;
    int lab = labels[b * 128 + t];
    int mk = mask_[b * 128 + t];
    float contrib;
    if (t == 0) {
        contrib = startv[lab] + em[b * 74 + lab];
    } else {
        int labp = labels[b * 128 + t - 1];
        contrib = mk ? (trans[labp * 74 + lab] + em[t * EMS_ + b * 74 + lab]) : 0.f;
    }
    float c = contrib; int m = mk;
    #pragma unroll
    for (int off = 32; off > 0; off >>= 1) {
        c += __shfl_xor(c, off);
        m += __shfl_xor(m, off);
    }
    if ((t & 63) == 0) { cs[t >> 6] = c; ms[t >> 6] = m; }
    __syncthreads();
    if (t == 0) {
        float num = cs[0] + cs[1];
        int msum = ms[0] + ms[1];
        int last = labels[b * 128 + msum - 1];
        num += endv[last];
        nd[b] = num - den[b];
    }
}

__global__ void loss_final(const float* __restrict__ nd, float* __restrict__ out_loss)
{
    __shared__ float red[256];
    int i = threadIdx.x;
    red[i] = nd[i];
    __syncthreads();
    for (int s = 128; s > 0; s >>= 1) { if (i < s) red[i] += red[i + s]; __syncthreads(); }
    if (i == 0) out_loss[0] = -(red[0] / 256.f);
}

extern "C" void kernel_launch(void* const* d_in, const int* in_sizes, int n_in,
                              void* d_out, int out_size, void* d_ws, size_t ws_size,
                              hipStream_t stream)
{
    const float* feats  = (const float*)d_in[0];
    const int*   amask  = (const int*)d_in[1];
    const int*   labels = (const int*)d_in[2];
    const float* cache  = (const float*)d_in[3];
    const float* W1     = (const float*)d_in[4];
    const float* b1     = (const float*)d_in[5];
    const float* W2     = (const float*)d_in[6];
    const float* b2     = (const float*)d_in[7];
    const float* startv = (const float*)d_in[8];
    const float* endv   = (const float*)d_in[9];
    const float* trans  = (const float*)d_in[10];

    float* ws     = (float*)d_ws;
    float* logits = ws;                 // 2,424,832
    float* y      = ws + 2424832;       // 2,424,832 (K-split partial B, then sim part[64], then y)
    float* em     = ws + 4849664;       // 2,424,832
    float* scratch= ws + 7274496;       // 1,048,576 (W1q alias; free after gemm_logits_part)
    float* sim    = ws + 8323072;       // 32,768
    float* p      = ws + 8355840;       // 32,768
    float* den    = ws + 8388608;       // 256
    float* nd     = ws + 8388864;       // 256
    float* W2q    = ws + 8389120;       // 5,920
    float* W1q    = scratch;            // 61,440 — dead before sim_partial runs
    float* part   = y;                  // 64*32768 = 2,097,152 ≤ 2,424,832; y dead after logits_sum
    float* out_tags = (float*)d_out;
    float* out_loss = (float*)d_out + 32768;

    hipLaunchKernelGGL(pad_weights,      dim3(240),  dim3(256), 0, stream, W1, W2, W1q, W2q);
    hipLaunchKernelGGL(gemm_logits_part, dim3(1024), dim3(256), 0, stream, feats, W1q, logits, y);
    hipLaunchKernelGGL(logits_sum,       dim3(9472), dim3(256), 0, stream, y, b1, logits);
    hipLaunchKernelGGL(sim_partial,      dim3(512),  dim3(256), 0, stream, logits, cache, part);
    hipLaunchKernelGGL(sim_reduce,       dim3(128),  dim3(256), 0, stream, part, sim);
    hipLaunchKernelGGL(softmax128,       dim3(256),  dim3(128), 0, stream, sim, p);
    hipLaunchKernelGGL(gemm_h_y,         dim3(592),  dim3(256), 0, stream, p, cache, logits, y);
    hipLaunchKernelGGL(gemm_em,          dim3(512),  dim3(256), 0, stream, y, W2q, b2, em);
    hipLaunchKernelGGL(crf_scan,         dim3(512),  dim3(256), 0, stream, em, amask, startv, endv, trans, out_tags, den);
    hipLaunchKernelGGL(loss_partial,     dim3(256),  dim3(128), 0, stream, em, labels, amask, startv, endv, den, trans, nd);
    hipLaunchKernelGGL(loss_final,       dim3(1),    dim3(256), 0, stream, nd, out_loss);
}